// Round 4
// baseline (2309.332 us; speedup 1.0000x reference)
//
#include <hip/hip_runtime.h>

// R4: threshold-collect top-k (exact via fallback), no LDS sim transpose,
// conversion fused into gemm. Problem constants fixed by setup_inputs.
#define BROWS 256
#define NCOLS 131072
#define DDIM  128
#define K     5
#define MARGIN 0.3f

#define NBLK  512                // gemm grid: 2 blocks/CU
#define CPB   (NCOLS / NBLK)     // 256 cols per block
#define NIT   (CPB / 16)         // 16 iters of 16 cols
#define TCOLL 40.0f              // collect threshold: sims ~N(0,128); p(v>40)~2e-4 -> E~26-60/row
#define CAP   128                // per-row candidate capacity (overflow -> exact fallback)
#define YSTR  68                 // ybf col stride in words (64 data + 4 pad: balanced banks)

typedef __attribute__((ext_vector_type(8))) __bf16 bf16x8;
typedef __attribute__((ext_vector_type(4))) float f32x4;
typedef __attribute__((ext_vector_type(4))) unsigned int u32x4;

// two fp32 -> packed bf16 word (lo=a, hi=b), round-to-nearest-even
__device__ __forceinline__ unsigned pack_bf16(float a, float b) {
    unsigned ua = __float_as_uint(a), ub = __float_as_uint(b);
    unsigned ra = (ua + 0x7fffu + ((ua >> 16) & 1u)) >> 16;
    unsigned rb = (ub + 0x7fffu + ((ub >> 16) & 1u)) & 0xffff0000u;
    return ra | rb;
}

__device__ __forceinline__ u32x4 pack8(const float4& a, const float4& b) {
    u32x4 t;
    t[0] = pack_bf16(a.x, a.y); t[1] = pack_bf16(a.z, a.w);
    t[2] = pack_bf16(b.x, b.y); t[3] = pack_bf16(b.z, b.w);
    return t;
}

// ---- Pass 1: bf16 MFMA gemm + threshold collection --------------------------
__global__ __launch_bounds__(256, 2) void gemm_collect_kernel(
    const float* __restrict__ x, const float* __restrict__ y,
    int* __restrict__ cnt, float* __restrict__ bufv, int* __restrict__ bufc)
{
    __shared__ unsigned ybf[2][16 * YSTR];   // double-buffered bf16 y tile, 2x4.25 KB

    const int tid   = threadIdx.x;
    const int lane  = tid & 63;
    const int quad  = lane >> 4;
    const int l15   = lane & 15;
    const int wrow0 = tid & 192;             // wave_id*64
    const int col0  = blockIdx.x * CPB;

    // A fragments: x fp32 -> bf16 once, register-resident. A[m=l15][k=quad*8+j].
    bf16x8 af[4][4];
#pragma unroll
    for (int mt = 0; mt < 4; ++mt) {
        const float* xp = x + (size_t)(wrow0 + mt * 16 + l15) * DDIM + quad * 8;
#pragma unroll
        for (int s = 0; s < 4; ++s) {
            const float4 a = *(const float4*)(xp + s * 32);
            const float4 b = *(const float4*)(xp + s * 32 + 4);
            const u32x4 t = pack8(a, b);
            af[mt][s] = __builtin_bit_cast(bf16x8, t);
        }
    }

    // staging: thread (sc=col-in-tile, sj=k-group) loads 8 fp32, converts, writes one b128
    const int sc = tid >> 4, sj = tid & 15;
    const float* ysrc = y + (size_t)(col0 + sc) * DDIM + sj * 8;
    const unsigned sdst = sc * YSTR + sj * 4;           // word offset in a buffer
    const unsigned frag_off = l15 * YSTR + quad * 4;    // + s*16

    float4 ga = *(const float4*)(ysrc);
    float4 gb = *(const float4*)(ysrc + 4);
    *(u32x4*)(&ybf[0][0] + sdst) = pack8(ga, gb);

    for (int it = 0; it < NIT; ++it) {
        if (it + 1 < NIT) {                  // issue next tile's global loads early
            const float* yn = ysrc + (size_t)(it + 1) * 16 * DDIM;
            ga = *(const float4*)(yn);
            gb = *(const float4*)(yn + 4);
        }
        __syncthreads();                     // ybf[it&1] visible; prev reads of ybf[(it+1)&1] done

        const unsigned* yb = &ybf[it & 1][0];
        bf16x8 bfrag[4];
#pragma unroll
        for (int s = 0; s < 4; ++s)
            bfrag[s] = __builtin_bit_cast(bf16x8, *(const u32x4*)(yb + frag_off + s * 16));

        f32x4 acc[4];
#pragma unroll
        for (int mt = 0; mt < 4; ++mt) acc[mt] = (f32x4){0.f, 0.f, 0.f, 0.f};
#pragma unroll
        for (int s = 0; s < 4; ++s)
#pragma unroll
            for (int mt = 0; mt < 4; ++mt)
                acc[mt] = __builtin_amdgcn_mfma_f32_16x16x32_bf16(af[mt][s], bfrag[s], acc[mt], 0, 0, 0);

        if (it + 1 < NIT)                    // convert + stage next tile (other buffer)
            *(u32x4*)(&ybf[(it + 1) & 1][0] + sdst) = pack8(ga, gb);

        // collect: lane's 16 acc values all share col = col0 + it*16 + l15.
        // Common path: max16 + one compare; body taken ~20% of wave-iters.
        float m = acc[0][0];
#pragma unroll
        for (int mt = 0; mt < 4; ++mt)
#pragma unroll
            for (int r = 0; r < 4; ++r) m = fmaxf(m, acc[mt][r]);
        if (m > TCOLL) {
            const int col = col0 + it * 16 + l15;
#pragma unroll
            for (int mt = 0; mt < 4; ++mt)
#pragma unroll
                for (int r = 0; r < 4; ++r) {
                    const float v = acc[mt][r];
                    if (v > TCOLL) {
                        const int row = wrow0 + mt * 16 + quad * 4 + r;
                        const int idx = atomicAdd(&cnt[row], 1);
                        if (idx < CAP) {
                            bufv[row * CAP + idx] = v;
                            bufc[row * CAP + idx] = col;
                        }
                    }
                }
        }
    }
}

// ---- shared epilogue helpers ------------------------------------------------
__device__ __forceinline__ void insert5(float* t5, float v) {
    if (v > t5[K - 1]) {
        float nv = v;
#pragma unroll
        for (int p = 0; p < K; ++p) {
            const bool gt = nv > t5[p];
            const float tv = t5[p];
            if (gt) { t5[p] = nv; nv = tv; }
        }
    }
}

__device__ __forceinline__ void merge5(float* __restrict__ t5, const float* __restrict__ src) {
#pragma unroll
    for (int p = 0; p < K; ++p) insert5(t5, src[p]);
}

__device__ __forceinline__ float epilogue(const float* t5, float sp) {
    float loss[K], logit[K];
#pragma unroll
    for (int p = 0; p < K; ++p) {
        loss[p]  = fmaxf(0.f, t5[p] - sp + MARGIN);
        logit[p] = (loss[p] != 0.f) ? t5[p] : 0.f;   // sim_n * mask, as reference
    }
    float mx = logit[0];
#pragma unroll
    for (int p = 1; p < K; ++p) mx = fmaxf(mx, logit[p]);
    float den = 0.f, num = 0.f;
#pragma unroll
    for (int p = 0; p < K; ++p) {
        const float e = __expf(logit[p] - mx);
        den += e;
        num += loss[p] * e;
    }
    return num / den;
}

// ---- Pass 2: per-row exact top-5 from candidate list + loss -----------------
__global__ __launch_bounds__(256) void reduce_kernel(
    const float* __restrict__ x, const float* __restrict__ y,
    const int* __restrict__ pos, const int* __restrict__ cnt,
    const float* __restrict__ bufv, const int* __restrict__ bufc,
    int* __restrict__ flag, float* __restrict__ out)
{
    const int row = blockIdx.x;
    const int tid = threadIdx.x;
    __shared__ float sred[256];
    __shared__ float sv[256 * K];

    // sim_p = fp32 dot(x[row], y[pos[row]]) — closer to reference than bf16
    const int prow = pos[row];
    float p = 0.f;
    if (tid < DDIM) p = x[row * DDIM + tid] * y[(size_t)prow * DDIM + tid];
    sred[tid] = p;
    __syncthreads();
    for (int s = 128; s >= 1; s >>= 1) {
        if (tid < s) sred[tid] += sred[tid + s];
        __syncthreads();
    }

    const int c = cnt[row];
    const int n = c < CAP ? c : CAP;
    float t5[K];
#pragma unroll
    for (int q = 0; q < K; ++q) t5[q] = -3.0e38f;
    if (tid < n && bufc[row * CAP + tid] != prow)
        t5[0] = bufv[row * CAP + tid];   // one entry per thread (CAP <= 256)

#pragma unroll
    for (int q = 0; q < K; ++q) sv[tid * K + q] = t5[q];
    __syncthreads();
    for (int s = 128; s >= 1; s >>= 1) {
        if (tid < s) {
            merge5(t5, &sv[(tid + s) * K]);
#pragma unroll
            for (int q = 0; q < K; ++q) sv[tid * K + q] = t5[q];
        }
        __syncthreads();
    }

    if (tid == 0) {
        // exact iff no overflow and >=5 valid survivors (all candidates > TCOLL > -1e38)
        const bool ok = (c <= CAP) && (t5[K - 1] > -1.0e38f);
        flag[row] = ok ? 0 : 1;
        if (ok) atomicAdd(out, epilogue(t5, sred[0]) * (1.0f / (BROWS * K)));
    }
}

// ---- Pass 3: exactness insurance — brute-force rows the collector missed ----
__global__ __launch_bounds__(256) void fallback_kernel(
    const float* __restrict__ x, const float* __restrict__ y,
    const int* __restrict__ pos, const int* __restrict__ flag,
    float* __restrict__ out)
{
    const int row = blockIdx.x;
    if (flag[row] == 0) return;              // normal case: immediate exit
    const int tid = threadIdx.x;
    const int prow = pos[row];
    __shared__ float xr[DDIM];
    __shared__ float sv[256 * K];
    if (tid < DDIM) xr[tid] = x[row * DDIM + tid];
    __syncthreads();

    float t5[K];
#pragma unroll
    for (int q = 0; q < K; ++q) t5[q] = -3.0e38f;
    for (int col = tid; col < NCOLS; col += 256) {
        if (col == prow) continue;
        const float* yp = y + (size_t)col * DDIM;
        float d = 0.f;
        for (int k = 0; k < DDIM; ++k) d = fmaf(xr[k], yp[k], d);
        insert5(t5, d);
    }
#pragma unroll
    for (int q = 0; q < K; ++q) sv[tid * K + q] = t5[q];
    __syncthreads();
    for (int s = 128; s >= 1; s >>= 1) {
        if (tid < s) {
            merge5(t5, &sv[(tid + s) * K]);
#pragma unroll
            for (int q = 0; q < K; ++q) sv[tid * K + q] = t5[q];
        }
        __syncthreads();
    }
    if (tid == 0) {
        float sp = 0.f;
        const float* yp = y + (size_t)prow * DDIM;
        for (int k = 0; k < DDIM; ++k) sp = fmaf(xr[k], yp[k], sp);
        atomicAdd(out, epilogue(t5, sp) * (1.0f / (BROWS * K)));
    }
}

extern "C" void kernel_launch(void* const* d_in, const int* in_sizes, int n_in,
                              void* d_out, int out_size, void* d_ws, size_t ws_size,
                              hipStream_t stream) {
    const float* x  = (const float*)d_in[0];   // [256,128] fp32
    const float* y  = (const float*)d_in[1];   // [131072,128] fp32
    // d_in[2] (target) is redundant (one-hot of pos_inds) — never read.
    const int* pos  = (const int*)d_in[3];     // [256] int32
    // d_in[4] (num_neg) fixed at 5 — compile-time K.

    int*   cnt  = (int*)d_ws;                          // 256 ints
    int*   flag = cnt + BROWS;                         // 256 ints
    float* bufv = (float*)(flag + BROWS);              // 256*CAP floats (128 KB)
    int*   bufc = (int*)(bufv + (size_t)BROWS * CAP);  // 256*CAP ints

    hipMemsetAsync(cnt, 0, BROWS * sizeof(int), stream);
    hipMemsetAsync(d_out, 0, sizeof(float), stream);

    gemm_collect_kernel<<<dim3(NBLK), 256, 0, stream>>>(x, y, cnt, bufv, bufc);
    reduce_kernel<<<dim3(BROWS), 256, 0, stream>>>(x, y, pos, cnt, bufv, bufc, flag, (float*)d_out);
    fallback_kernel<<<dim3(BROWS), 256, 0, stream>>>(x, y, pos, flag, (float*)d_out);
}

// Round 5
// 237.211 us; speedup vs baseline: 9.7354x; 9.7354x over previous
//
#include <hip/hip_runtime.h>

// R5: threshold-collect top-k with ROW-ADAPTIVE threshold z*||x_row||
// (R4's fixed threshold failed: sim|x ~ N(0,||x||^2), ||x||^2 ~ chi2(128) ->
//  big-norm rows overflowed CAP, small-norm rows had <5 survivors; 4 rows
//  hit the 67MB brute-force fallback = 2.1ms). Exactness via fallback kept.
#define BROWS 256
#define NCOLS 131072
#define DDIM  128
#define K     5
#define MARGIN 0.3f

#define NBLK  512                // gemm grid: 2 blocks/CU
#define CPB   (NCOLS / NBLK)     // 256 cols per block
#define NIT   (CPB / 16)         // 16 iters of 16 cols
#define ZGATE 3.4f               // per-row gate z-score: E[count] = 131071*P(Z>3.4) ~ 44
#define CAP   128                // per-row candidate capacity (Poisson(44) > 128: ~1e-30)
#define YSTR  68                 // ybf col stride in words (64 data + 4 pad)

typedef __attribute__((ext_vector_type(8))) __bf16 bf16x8;
typedef __attribute__((ext_vector_type(4))) float f32x4;
typedef __attribute__((ext_vector_type(4))) unsigned int u32x4;

// two fp32 -> packed bf16 word (lo=a, hi=b), round-to-nearest-even
__device__ __forceinline__ unsigned pack_bf16(float a, float b) {
    unsigned ua = __float_as_uint(a), ub = __float_as_uint(b);
    unsigned ra = (ua + 0x7fffu + ((ua >> 16) & 1u)) >> 16;
    unsigned rb = (ub + 0x7fffu + ((ub >> 16) & 1u)) & 0xffff0000u;
    return ra | rb;
}

__device__ __forceinline__ u32x4 pack8(const float4& a, const float4& b) {
    u32x4 t;
    t[0] = pack_bf16(a.x, a.y); t[1] = pack_bf16(a.z, a.w);
    t[2] = pack_bf16(b.x, b.y); t[3] = pack_bf16(b.z, b.w);
    return t;
}

// ---- Pass 0: per-row thresholds + zero cnt/out (replaces two memsets) -------
__global__ __launch_bounds__(256) void init_kernel(
    const float* __restrict__ x, float* __restrict__ thr,
    int* __restrict__ cnt, float* __restrict__ out)
{
    const int t = threadIdx.x;
    const float* xp = x + (size_t)t * DDIM;
    float s = 0.f;
#pragma unroll
    for (int k = 0; k < DDIM; k += 4) {
        const float4 v = *(const float4*)(xp + k);
        s = fmaf(v.x, v.x, s); s = fmaf(v.y, v.y, s);
        s = fmaf(v.z, v.z, s); s = fmaf(v.w, v.w, s);
    }
    thr[t] = ZGATE * sqrtf(s);
    cnt[t] = 0;
    if (t == 0) out[0] = 0.f;
}

// ---- Pass 1: bf16 MFMA gemm + adaptive threshold collection -----------------
__global__ __launch_bounds__(256, 2) void gemm_collect_kernel(
    const float* __restrict__ x, const float* __restrict__ y,
    const float* __restrict__ thr,
    int* __restrict__ cnt, float* __restrict__ bufv, int* __restrict__ bufc)
{
    __shared__ unsigned ybf[2][16 * YSTR];   // double-buffered bf16 y tile, 2x4.25 KB

    const int tid   = threadIdx.x;
    const int lane  = tid & 63;
    const int quad  = lane >> 4;
    const int l15   = lane & 15;
    const int wrow0 = tid & 192;             // wave_id*64
    const int col0  = blockIdx.x * CPB;

    // A fragments: x fp32 -> bf16 once, register-resident. A[m=l15][k=quad*8+j].
    bf16x8 af[4][4];
#pragma unroll
    for (int mt = 0; mt < 4; ++mt) {
        const float* xp = x + (size_t)(wrow0 + mt * 16 + l15) * DDIM + quad * 8;
#pragma unroll
        for (int s = 0; s < 4; ++s) {
            const float4 a = *(const float4*)(xp + s * 32);
            const float4 b = *(const float4*)(xp + s * 32 + 4);
            const u32x4 t = pack8(a, b);
            af[mt][s] = __builtin_bit_cast(bf16x8, t);
        }
    }

    // per-row gate thresholds for the 16 acc rows this lane owns
    float thrv[16];
#pragma unroll
    for (int mt = 0; mt < 4; ++mt)
#pragma unroll
        for (int r = 0; r < 4; ++r)
            thrv[mt * 4 + r] = thr[wrow0 + mt * 16 + quad * 4 + r];

    // staging: thread (sc=col-in-tile, sj=k-group) loads 8 fp32, converts, writes one b128
    const int sc = tid >> 4, sj = tid & 15;
    const float* ysrc = y + (size_t)(col0 + sc) * DDIM + sj * 8;
    const unsigned sdst = sc * YSTR + sj * 4;           // word offset in a buffer
    const unsigned frag_off = l15 * YSTR + quad * 4;    // + s*16

    float4 ga = *(const float4*)(ysrc);
    float4 gb = *(const float4*)(ysrc + 4);
    *(u32x4*)(&ybf[0][0] + sdst) = pack8(ga, gb);

    for (int it = 0; it < NIT; ++it) {
        if (it + 1 < NIT) {                  // issue next tile's global loads early
            const float* yn = ysrc + (size_t)(it + 1) * 16 * DDIM;
            ga = *(const float4*)(yn);
            gb = *(const float4*)(yn + 4);
        }
        __syncthreads();                     // ybf[it&1] visible; prev reads of other buf done

        const unsigned* yb = &ybf[it & 1][0];
        bf16x8 bfrag[4];
#pragma unroll
        for (int s = 0; s < 4; ++s)
            bfrag[s] = __builtin_bit_cast(bf16x8, *(const u32x4*)(yb + frag_off + s * 16));

        f32x4 acc[4];
#pragma unroll
        for (int mt = 0; mt < 4; ++mt) acc[mt] = (f32x4){0.f, 0.f, 0.f, 0.f};
#pragma unroll
        for (int s = 0; s < 4; ++s)
#pragma unroll
            for (int mt = 0; mt < 4; ++mt)
                acc[mt] = __builtin_amdgcn_mfma_f32_16x16x32_bf16(af[mt][s], bfrag[s], acc[mt], 0, 0, 0);

        if (it + 1 < NIT)                    // convert + stage next tile (other buffer)
            *(u32x4*)(&ybf[(it + 1) & 1][0] + sdst) = pack8(ga, gb);

        // collect: lane's 16 acc values all share col = col0 + it*16 + l15.
        // Common path: 16 sub + max + 1 cmp; body taken ~29% of wave-iters.
        float m = -1.f;
#pragma unroll
        for (int mt = 0; mt < 4; ++mt)
#pragma unroll
            for (int r = 0; r < 4; ++r)
                m = fmaxf(m, acc[mt][r] - thrv[mt * 4 + r]);
        if (m > 0.f) {
            const int col = col0 + it * 16 + l15;
#pragma unroll
            for (int mt = 0; mt < 4; ++mt)
#pragma unroll
                for (int r = 0; r < 4; ++r) {
                    const float v = acc[mt][r];
                    if (v > thrv[mt * 4 + r]) {
                        const int row = wrow0 + mt * 16 + quad * 4 + r;
                        const int idx = atomicAdd(&cnt[row], 1);
                        if (idx < CAP) {
                            bufv[row * CAP + idx] = v;
                            bufc[row * CAP + idx] = col;
                        }
                    }
                }
        }
    }
}

// ---- shared epilogue helpers ------------------------------------------------
__device__ __forceinline__ void insert5(float* t5, float v) {
    if (v > t5[K - 1]) {
        float nv = v;
#pragma unroll
        for (int p = 0; p < K; ++p) {
            const bool gt = nv > t5[p];
            const float tv = t5[p];
            if (gt) { t5[p] = nv; nv = tv; }
        }
    }
}

__device__ __forceinline__ void merge5(float* __restrict__ t5, const float* __restrict__ src) {
#pragma unroll
    for (int p = 0; p < K; ++p) insert5(t5, src[p]);
}

__device__ __forceinline__ float epilogue(const float* t5, float sp) {
    float loss[K], logit[K];
#pragma unroll
    for (int p = 0; p < K; ++p) {
        loss[p]  = fmaxf(0.f, t5[p] - sp + MARGIN);
        logit[p] = (loss[p] != 0.f) ? t5[p] : 0.f;   // sim_n * mask, as reference
    }
    float mx = logit[0];
#pragma unroll
    for (int p = 1; p < K; ++p) mx = fmaxf(mx, logit[p]);
    float den = 0.f, num = 0.f;
#pragma unroll
    for (int p = 0; p < K; ++p) {
        const float e = __expf(logit[p] - mx);
        den += e;
        num += loss[p] * e;
    }
    return num / den;
}

// ---- Pass 2: per-row exact top-5 from candidate list + loss -----------------
__global__ __launch_bounds__(256) void reduce_kernel(
    const float* __restrict__ x, const float* __restrict__ y,
    const int* __restrict__ pos, const int* __restrict__ cnt,
    const float* __restrict__ bufv, const int* __restrict__ bufc,
    int* __restrict__ flag, float* __restrict__ out)
{
    const int row = blockIdx.x;
    const int tid = threadIdx.x;
    __shared__ float sred[256];
    __shared__ float sv[256 * K];

    // sim_p = fp32 dot(x[row], y[pos[row]])
    const int prow = pos[row];
    float p = 0.f;
    if (tid < DDIM) p = x[row * DDIM + tid] * y[(size_t)prow * DDIM + tid];
    sred[tid] = p;
    __syncthreads();
    for (int s = 128; s >= 1; s >>= 1) {
        if (tid < s) sred[tid] += sred[tid + s];
        __syncthreads();
    }

    const int c = cnt[row];
    const int n = c < CAP ? c : CAP;
    float t5[K];
#pragma unroll
    for (int q = 0; q < K; ++q) t5[q] = -3.0e38f;
    if (tid < n && bufc[row * CAP + tid] != prow)
        t5[0] = bufv[row * CAP + tid];   // one entry per thread (CAP <= 256)

#pragma unroll
    for (int q = 0; q < K; ++q) sv[tid * K + q] = t5[q];
    __syncthreads();
    for (int s = 128; s >= 1; s >>= 1) {
        if (tid < s) {
            merge5(t5, &sv[(tid + s) * K]);
#pragma unroll
            for (int q = 0; q < K; ++q) sv[tid * K + q] = t5[q];
        }
        __syncthreads();
    }

    if (tid == 0) {
        // exact iff no overflow and >=5 valid survivors
        const bool ok = (c <= CAP) && (t5[K - 1] > -1.0e38f);
        flag[row] = ok ? 0 : 1;
        if (ok) atomicAdd(out, epilogue(t5, sred[0]) * (1.0f / (BROWS * K)));
    }
}

// ---- Pass 3: exactness insurance — brute-force rows the collector missed ----
__global__ __launch_bounds__(256) void fallback_kernel(
    const float* __restrict__ x, const float* __restrict__ y,
    const int* __restrict__ pos, const int* __restrict__ flag,
    float* __restrict__ out)
{
    const int row = blockIdx.x;
    if (flag[row] == 0) return;              // normal case: immediate exit
    const int tid = threadIdx.x;
    const int prow = pos[row];
    __shared__ float xr[DDIM];
    __shared__ float sv[256 * K];
    if (tid < DDIM) xr[tid] = x[row * DDIM + tid];
    __syncthreads();

    float t5[K];
#pragma unroll
    for (int q = 0; q < K; ++q) t5[q] = -3.0e38f;
    for (int col = tid; col < NCOLS; col += 256) {
        if (col == prow) continue;
        const float* yp = y + (size_t)col * DDIM;
        float d = 0.f;
        for (int k = 0; k < DDIM; ++k) d = fmaf(xr[k], yp[k], d);
        insert5(t5, d);
    }
#pragma unroll
    for (int q = 0; q < K; ++q) sv[tid * K + q] = t5[q];
    __syncthreads();
    for (int s = 128; s >= 1; s >>= 1) {
        if (tid < s) {
            merge5(t5, &sv[(tid + s) * K]);
#pragma unroll
            for (int q = 0; q < K; ++q) sv[tid * K + q] = t5[q];
        }
        __syncthreads();
    }
    if (tid == 0) {
        float sp = 0.f;
        const float* yp = y + (size_t)prow * DDIM;
        for (int k = 0; k < DDIM; ++k) sp = fmaf(xr[k], yp[k], sp);
        atomicAdd(out, epilogue(t5, sp) * (1.0f / (BROWS * K)));
    }
}

extern "C" void kernel_launch(void* const* d_in, const int* in_sizes, int n_in,
                              void* d_out, int out_size, void* d_ws, size_t ws_size,
                              hipStream_t stream) {
    const float* x  = (const float*)d_in[0];   // [256,128] fp32
    const float* y  = (const float*)d_in[1];   // [131072,128] fp32
    // d_in[2] (target) is redundant (one-hot of pos_inds) — never read.
    const int* pos  = (const int*)d_in[3];     // [256] int32
    // d_in[4] (num_neg) fixed at 5 — compile-time K.

    int*   cnt  = (int*)d_ws;                          // 256 ints
    int*   flag = cnt + BROWS;                         // 256 ints
    float* thr  = (float*)(flag + BROWS);              // 256 floats
    float* bufv = thr + BROWS;                         // 256*CAP floats (128 KB)
    int*   bufc = (int*)(bufv + (size_t)BROWS * CAP);  // 256*CAP ints

    init_kernel<<<dim3(1), 256, 0, stream>>>(x, thr, cnt, (float*)d_out);
    gemm_collect_kernel<<<dim3(NBLK), 256, 0, stream>>>(x, y, thr, cnt, bufv, bufc);
    reduce_kernel<<<dim3(BROWS), 256, 0, stream>>>(x, y, pos, cnt, bufv, bufc, flag, (float*)d_out);
    fallback_kernel<<<dim3(BROWS), 256, 0, stream>>>(x, y, pos, flag, (float*)d_out);
}